// Round 1
// baseline (103.779 us; speedup 1.0000x reference)
//
#include <hip/hip_runtime.h>
#include <math.h>

// Problem constants (fixed by setup_inputs): B=8, N=2048, coords [B,N,3] f32.
constexpr int B = 8;
constexpr int N = 2048;
constexpr int TI = 256;   // i-points per block == threads per block
constexpr int TJ = 128;   // j-points staged in LDS per block

// ws layout: float partial[B][2] = {num, den}
__global__ __launch_bounds__(TI) void lddt_partial(
    const float* __restrict__ pred,   // [B,N,3]
    const float* __restrict__ truec,  // [B,N,3]
    float* __restrict__ partial)      // [B,2]
{
    const int b  = blockIdx.z;
    const int i0 = blockIdx.y * TI;
    const int j0 = blockIdx.x * TJ;
    const int t  = threadIdx.x;

    __shared__ float pj[TJ][3];
    __shared__ float tj[TJ][3];

    if (t < TJ) {
        const float* pp = pred  + ((size_t)b * N + j0 + t) * 3;
        const float* tp = truec + ((size_t)b * N + j0 + t) * 3;
        pj[t][0] = pp[0]; pj[t][1] = pp[1]; pj[t][2] = pp[2];
        tj[t][0] = tp[0]; tj[t][1] = tp[1]; tj[t][2] = tp[2];
    }
    __syncthreads();

    const int i = i0 + t;
    const float* pi = pred  + ((size_t)b * N + i) * 3;
    const float* ti = truec + ((size_t)b * N + i) * 3;
    const float pix = pi[0], piy = pi[1], piz = pi[2];
    const float tix = ti[0], tiy = ti[1], tiz = ti[2];

    float num = 0.0f, den = 0.0f;

    #pragma unroll 8
    for (int j = 0; j < TJ; ++j) {
        float dx = pix - pj[j][0];
        float dy = piy - pj[j][1];
        float dz = piz - pj[j][2];
        float pd2 = dx * dx + dy * dy + dz * dz;

        float ex = tix - tj[j][0];
        float ey = tiy - tj[j][1];
        float ez = tiz - tj[j][2];
        float td2 = ex * ex + ey * ey + ez * ez;

        // mask: true_d < 15 && true_d > 1e-8  (compare in squared domain)
        bool m = (td2 < 225.0f) && (td2 > 1e-16f);

        float diff = fabsf(__builtin_amdgcn_sqrtf(pd2) - __builtin_amdgcn_sqrtf(td2));
        float s = diff < 0.5f ? 1.0f
                : diff < 1.0f ? 0.5f
                : diff < 2.0f ? 0.25f
                : diff < 4.0f ? 0.125f
                : 0.0f;

        num += m ? s    : 0.0f;
        den += m ? 1.0f : 0.0f;
    }

    // wave (64-lane) shuffle reduction, then cross-wave via LDS
    for (int off = 32; off > 0; off >>= 1) {
        num += __shfl_down(num, off, 64);
        den += __shfl_down(den, off, 64);
    }

    __shared__ float rnum[TI / 64];
    __shared__ float rden[TI / 64];
    const int wave = t >> 6;
    const int lane = t & 63;
    if (lane == 0) { rnum[wave] = num; rden[wave] = den; }
    __syncthreads();

    if (t == 0) {
        float n = 0.0f, d = 0.0f;
        #pragma unroll
        for (int w = 0; w < TI / 64; ++w) { n += rnum[w]; d += rden[w]; }
        atomicAdd(&partial[2 * b + 0], n);
        atomicAdd(&partial[2 * b + 1], d);
    }
}

__global__ void lddt_final(const float* __restrict__ partial,
                           float* __restrict__ out)
{
    if (threadIdx.x == 0) {
        float acc = 0.0f;
        #pragma unroll
        for (int b = 0; b < B; ++b) {
            float n = partial[2 * b + 0];
            float d = partial[2 * b + 1];
            d = fmaxf(d, 1e-8f);
            acc += 1.0f - n / d;
        }
        out[0] = acc / (float)B;
    }
}

extern "C" void kernel_launch(void* const* d_in, const int* in_sizes, int n_in,
                              void* d_out, int out_size, void* d_ws, size_t ws_size,
                              hipStream_t stream)
{
    const float* pred  = (const float*)d_in[0];
    const float* truec = (const float*)d_in[1];
    float* out = (float*)d_out;
    float* partial = (float*)d_ws;

    hipMemsetAsync(partial, 0, B * 2 * sizeof(float), stream);

    dim3 grid(N / TJ, N / TI, B);   // 16 x 8 x 8 = 1024 blocks
    lddt_partial<<<grid, TI, 0, stream>>>(pred, truec, partial);
    lddt_final<<<1, 64, 0, stream>>>(partial, out);
}